// Round 6
// baseline (259.187 us; speedup 1.0000x reference)
//
#include <hip/hip_runtime.h>
#include <hip/hip_bf16.h>

#define NR 16384
#define CC 2048
#define NV 6
#define MOMENT_F 1.6384f      // N/10000
#define RPB 16                // rows per k1 block (one view per block)
#define K1_GRID 1032          // >= sum_v ceil(cnt_v/RPB) (<=1029 worst case)

// ws layout (bytes):
//   [0,      65536)  sidx  int[NR]      row indices sorted (grouped) by view
//   [65536,  65792)  meta  int[64]      [0..6]=vstart, [8..14]=blockStart,
//                                       [16..21]=cnt
//   [65792,  70016)  btag  int[K1_GRID] per-block view tag (6 = unused)
//   [70016,  ...  )  part  float[K1_GRID*4096] per-block [2048 sum][2048 sq]

// ---------------------------------------------------------------------------
// P0: 1 block x 1024 thr (16 waves). Wave w owns rows [w*1024,(w+1)*1024).
// Pass 1: per-wave per-view counts via ballot. Thread 0: prefix sums ->
// vstart/blockStart/cnt (meta) + per-wave scatter bases. Pass 2: rank-order
// scatter of row indices into sidx. Also zeroes out (K2 atomicAdds later).
// ---------------------------------------------------------------------------
__global__ __launch_bounds__(1024) void p0_sort(
    const int* __restrict__ views, int* __restrict__ sidx,
    int* __restrict__ meta, float* __restrict__ out) {
  const int t = threadIdx.x;
  const int w = t >> 6;
  const int lane = t & 63;
  const unsigned long long lmask = (1ull << lane) - 1ull;

  __shared__ int whist[16][8];
  __shared__ int wbase[16][8];

  int wc[NV] = {0, 0, 0, 0, 0, 0};
  for (int it = 0; it < 16; ++it) {
    int row = (w << 10) + (it << 6) + lane;
    int v = views[row];
#pragma unroll
    for (int vi = 0; vi < NV; ++vi) {
      unsigned long long m = __ballot(v == vi);
      wc[vi] += (int)__popcll(m);
    }
  }
  if (lane == 0)
#pragma unroll
    for (int vi = 0; vi < NV; ++vi) whist[w][vi] = wc[vi];
  __syncthreads();

  if (t == 0) {
    int cnt[NV];
#pragma unroll
    for (int v = 0; v < NV; ++v) {
      int c = 0;
      for (int ww = 0; ww < 16; ++ww) c += whist[ww][v];
      cnt[v] = c;
    }
    int vs = 0, bs = 0;
#pragma unroll
    for (int v = 0; v < NV; ++v) {
      meta[v] = vs;
      meta[8 + v] = bs;
      meta[16 + v] = cnt[v];
      // per-wave scatter bases for this view
      int run = vs;
      for (int ww = 0; ww < 16; ++ww) { wbase[ww][v] = run; run += whist[ww][v]; }
      vs += cnt[v];
      bs += (cnt[v] + RPB - 1) / RPB;
    }
    meta[NV] = vs;
    meta[8 + NV] = bs;
    out[0] = 0.f;
  }
  __syncthreads();

  int wrun[NV];
#pragma unroll
  for (int v = 0; v < NV; ++v) wrun[v] = wbase[w][v];
  for (int it = 0; it < 16; ++it) {
    int row = (w << 10) + (it << 6) + lane;
    int v = views[row];
#pragma unroll
    for (int vi = 0; vi < NV; ++vi) {
      unsigned long long m = __ballot(v == vi);
      if (v == vi) {
        int rank = (int)__popcll(m & lmask);
        sidx[wrun[vi] + rank] = row;
      }
      wrun[vi] += (int)__popcll(m);
    }
  }
}

// ---------------------------------------------------------------------------
// K1: 1032 blocks x 512 thr, VGPR-capped to 64 (8 waves/EU -> 32 waves/CU).
// Block b: single view v, 16 gathered rows (8 KB each, perfectly coalesced),
// ONE accumulator pair (8 VGPRs), 8 named loads in flight. Writes one 16 KB
// slab + view tag. 256 KB outstanding/CU -> HBM-BW-bound, not latency-bound.
// ---------------------------------------------------------------------------
__global__ __launch_bounds__(512, 8) void k1_stats(
    const float* __restrict__ x, const int* __restrict__ sidx,
    const int* __restrict__ meta, int* __restrict__ btag,
    float4* __restrict__ part4) {
  const int b = blockIdx.x;
  const int t = threadIdx.x;

  const int nb_used = meta[8 + NV];
  if (b >= nb_used) {
    if (t == 0) btag[b] = 6;
    return;
  }
  int v = 0;
#pragma unroll
  for (int u = 1; u < NV; ++u)
    if (b >= meta[8 + u]) v = u;
  const int cnt_v = meta[16 + v];
  const int i0 = (b - meta[8 + v]) * RPB;
  const int m = min(RPB, cnt_v - i0);
  const int base = meta[v] + i0;

  __shared__ int rlds[RPB];
  if (t < RPB) rlds[t] = (t < m) ? sidx[base + t] : 0;
  __syncthreads();

  const float4* xp = (const float4*)x + t;  // thread's column group (of 512)
  float4 sm = {0.f, 0.f, 0.f, 0.f};
  float4 sq = {0.f, 0.f, 0.f, 0.f};
  const float4 z4 = {0.f, 0.f, 0.f, 0.f};

#define LD(j) ((g + (j) < m) \
    ? xp[(size_t)__builtin_amdgcn_readfirstlane(rlds[g + (j)]) * 512] : z4)
#define ACC(bv) \
  sm.x += bv.x; sm.y += bv.y; sm.z += bv.z; sm.w += bv.w; \
  sq.x = fmaf(bv.x, bv.x, sq.x); sq.y = fmaf(bv.y, bv.y, sq.y); \
  sq.z = fmaf(bv.z, bv.z, sq.z); sq.w = fmaf(bv.w, bv.w, sq.w);

  for (int g = 0; g < RPB; g += 8) {
    float4 b0 = LD(0); float4 b1 = LD(1); float4 b2 = LD(2); float4 b3 = LD(3);
    float4 b4 = LD(4); float4 b5 = LD(5); float4 b6 = LD(6); float4 b7 = LD(7);
    ACC(b0) ACC(b1) ACC(b2) ACC(b3) ACC(b4) ACC(b5) ACC(b6) ACC(b7)
  }
#undef LD
#undef ACC

  float4* slab = part4 + (size_t)b * 1024;
  slab[t] = sm;
  slab[512 + t] = sq;
  if (t == 0) btag[b] = v;
}

// ---------------------------------------------------------------------------
// K2: 64 blocks x 1024 thr. Block owns 32 columns; thread (g=t>>5 in 0..31,
// cl=t&31): branchless tag-select partial reduction over 1032 slabs
// (33 iters, coalesced L3-resident reads). LDS-reduce over g, finish stats +
// loss per column, shuffle-reduce 32 lanes, one atomicAdd per block.
// ---------------------------------------------------------------------------
__global__ __launch_bounds__(1024) void k2_finish(
    const float* __restrict__ part, const int* __restrict__ btag,
    const int* __restrict__ meta,
    const float* __restrict__ cmean, const float* __restrict__ cstd,
    float* __restrict__ out) {
  const int t = threadIdx.x;
  const int g = t >> 5;
  const int cl = t & 31;
  const int c = blockIdx.x * 32 + cl;

  __shared__ int tlds[K1_GRID];
  for (int i = t; i < K1_GRID; i += 1024) tlds[i] = btag[i];
  __syncthreads();

  float su[NV] = {0.f, 0.f, 0.f, 0.f, 0.f, 0.f};
  float sq[NV] = {0.f, 0.f, 0.f, 0.f, 0.f, 0.f};
  for (int b = g; b < K1_GRID; b += 32) {
    int tag = tlds[b];
    float s = part[(size_t)b * 4096 + c];
    float q = part[(size_t)b * 4096 + 2048 + c];
#pragma unroll
    for (int v = 0; v < NV; ++v) {
      su[v] += (tag == v) ? s : 0.f;
      sq[v] += (tag == v) ? q : 0.f;
    }
  }

  __shared__ float red[32][32][2 * NV];  // 48 KB
#pragma unroll
  for (int v = 0; v < NV; ++v) {
    red[g][cl][v] = su[v];
    red[g][cl][NV + v] = sq[v];
  }
  __syncthreads();

  if (g == 0) {
    for (int gg = 1; gg < 32; ++gg)
#pragma unroll
      for (int v = 0; v < NV; ++v) {
        su[v] += red[gg][cl][v];
        sq[v] += red[gg][cl][NV + v];
      }

    float cnt[NV], nvalid = 0.f;
#pragma unroll
    for (int v = 0; v < NV; ++v) {
      cnt[v] = (float)meta[16 + v];
      nvalid += (cnt[v] > 1.5f) ? 1.f : 0.f;
    }

    float mean[NV], sd[NV], nm = 0.f, ns = 0.f;
#pragma unroll
    for (int v = 0; v < NV; ++v) {
      float n = fmaxf(cnt[v], 1.f);
      float mu = su[v] / n;
      float var = (sq[v] - cnt[v] * mu * mu) / fmaxf(cnt[v] - 1.f, 1.f);
      float sdv = sqrtf(fmaxf(var, 0.f));
      mean[v] = mu;
      sd[v] = sdv;
      if (cnt[v] > 1.5f) { nm += mu; ns += sdv; }
    }
    nm /= nvalid;
    ns /= nvalid;
    const float cm = cmean[c] * (1.f - MOMENT_F) + nm * MOMENT_F;
    const float cs = cstd[c]  * (1.f - MOMENT_F) + ns * MOMENT_F;

    float contrib = 0.f;
#pragma unroll
    for (int v = 0; v < NV; ++v)
      if (cnt[v] > 1.5f) {
        float d1 = mean[v] - cm;
        float d2 = sd[v] - cs;
        contrib += d1 * d1 + d2 * d2;
      }
    contrib /= (2.f * nvalid);

    for (int o = 16; o > 0; o >>= 1) contrib += __shfl_down(contrib, o, 32);
    if (cl == 0) atomicAdd(out, contrib);
  }
}

extern "C" void kernel_launch(void* const* d_in, const int* in_sizes, int n_in,
                              void* d_out, int out_size, void* d_ws, size_t ws_size,
                              hipStream_t stream) {
  const float* x     = (const float*)d_in[0];  // (N, C) f32
  const float* cmean = (const float*)d_in[1];  // (C,)  f32
  const float* cstd  = (const float*)d_in[2];  // (C,)  f32
  const int*   views = (const int*)d_in[3];    // (N,)  i32
  float* out = (float*)d_out;

  int*   sidx = (int*)d_ws;
  int*   meta = (int*)((char*)d_ws + 65536);
  int*   btag = (int*)((char*)d_ws + 65792);
  float* part = (float*)((char*)d_ws + 70016);

  p0_sort<<<1, 1024, 0, stream>>>(views, sidx, meta, out);
  k1_stats<<<K1_GRID, 512, 0, stream>>>(x, sidx, meta, btag, (float4*)part);
  k2_finish<<<CC / 32, 1024, 0, stream>>>(part, btag, meta, cmean, cstd, out);
}

// Round 7
// 250.885 us; speedup vs baseline: 1.0331x; 1.0331x over previous
//
#include <hip/hip_runtime.h>
#include <hip/hip_bf16.h>

#define NR 16384
#define CC 2048
#define NV 6
#define MOMENT_F 1.6384f      // N/10000
#define NBLK 512              // k1 blocks
#define RPB 32                // rows per k1 block
#define STG 2                 // rows per stage (16 KB)
#define NSTG (RPB / STG)      // 16 stages

// ws layout: [part: NBLK*NV*4096 floats = 50.3 MB][cnt: NBLK*8 floats]
// part slab b*NV+v : [2048 col-sums][2048 col-sqsums]. Fully overwritten.

typedef float __attribute__((address_space(1))) f32g;
typedef float __attribute__((address_space(3))) f32l;

// Async global->LDS 16B copy: per-lane global addr, wave-uniform LDS base;
// HW lands lane i at ldsbase + i*16. Zero VGPR cost, stays in vmcnt queue.
__device__ __forceinline__ void async_ld16(const float* g, float* l) {
  __builtin_amdgcn_global_load_lds((const f32g*)g, (f32l*)l, 16, 0, 0);
}

// ---------------------------------------------------------------------------
// K1: 512 blocks x 512 thr (2 blocks/CU). Block s owns 32 contiguous rows.
// Double-buffered async LDS staging (2 x 16 KB), consume with scalar-uniform
// row-mask branches into 6 register accumulator pairs. The async path keeps
// a full stage (16 KB/block) outstanding with no VGPR pressure — the fix for
// the depth-1 load pipelining seen in R1-R6 (VGPR_Count=32, 2.4 TB/s cap).
// ---------------------------------------------------------------------------
__global__ __launch_bounds__(512, 4) void k1_stats(
    const float* __restrict__ x, const int* __restrict__ views,
    float4* __restrict__ part4, float* __restrict__ cnt,
    float* __restrict__ out) {
  __shared__ float buf[2][STG * CC];   // 2 x 16 KB
  const int s = blockIdx.x;
  const int t = threadIdx.x;
  const int lane = t & 63;
  const int wb = t & ~63;              // wave-base thread index
  const int r0 = s * RPB;

  // Per-view row masks: bit j = (views[r0+j]==v), j in 0..31. Each wave
  // computes the identical wave-uniform masks from its low 32 lanes.
  const int myv = (lane < RPB) ? views[r0 + lane] : -1;
  const unsigned long long mv0 = __ballot(myv == 0);
  const unsigned long long mv1 = __ballot(myv == 1);
  const unsigned long long mv2 = __ballot(myv == 2);
  const unsigned long long mv3 = __ballot(myv == 3);
  const unsigned long long mv4 = __ballot(myv == 4);
  const unsigned long long mv5 = __ballot(myv == 5);
  if (t == 0) {
    cnt[s * 8 + 0] = (float)__popcll(mv0);
    cnt[s * 8 + 1] = (float)__popcll(mv1);
    cnt[s * 8 + 2] = (float)__popcll(mv2);
    cnt[s * 8 + 3] = (float)__popcll(mv3);
    cnt[s * 8 + 4] = (float)__popcll(mv4);
    cnt[s * 8 + 5] = (float)__popcll(mv5);
  }
  if (s == 0 && t == 511) out[0] = 0.f;   // k2 atomicAdds into out

  float4 sm[NV], sq[NV];
#pragma unroll
  for (int v = 0; v < NV; ++v) {
    sm[v] = make_float4(0.f, 0.f, 0.f, 0.f);
    sq[v] = make_float4(0.f, 0.f, 0.f, 0.f);
  }

  const float* xb = x + (size_t)r0 * CC;

  // prefetch stage 0
  async_ld16(xb + 4 * (size_t)t,      &buf[0][0] + 4 * wb);
  async_ld16(xb + CC + 4 * (size_t)t, &buf[0][CC] + 4 * wb);

#define ACC(v, d) \
  sm[v].x += d.x; sm[v].y += d.y; sm[v].z += d.z; sm[v].w += d.w; \
  sq[v].x = fmaf(d.x, d.x, sq[v].x); sq[v].y = fmaf(d.y, d.y, sq[v].y); \
  sq[v].z = fmaf(d.z, d.z, sq[v].z); sq[v].w = fmaf(d.w, d.w, sq[v].w);

  for (int st = 0; st < NSTG; ++st) {
    const int cur = st & 1;
    if (st + 1 < NSTG) {                 // prefetch next stage into other buf
      const float* xs = xb + (size_t)(st + 1) * STG * CC;
      async_ld16(xs + 4 * (size_t)t,      &buf[cur ^ 1][0] + 4 * wb);
      async_ld16(xs + CC + 4 * (size_t)t, &buf[cur ^ 1][CC] + 4 * wb);
    }
    __syncthreads();                     // stage data visible (vmcnt drain)
#pragma unroll
    for (int sub = 0; sub < STG; ++sub) {
      const int j = st * STG + sub;
      float4 d = ((const float4*)&buf[cur][sub * CC])[t];
      if ((mv0 >> j) & 1)      { ACC(0, d) }
      else if ((mv1 >> j) & 1) { ACC(1, d) }
      else if ((mv2 >> j) & 1) { ACC(2, d) }
      else if ((mv3 >> j) & 1) { ACC(3, d) }
      else if ((mv4 >> j) & 1) { ACC(4, d) }
      else                     { ACC(5, d) }
    }
    __syncthreads();                     // consume done before buf overwrite
  }
#undef ACC

#pragma unroll
  for (int v = 0; v < NV; ++v) {
    float4* slab = part4 + (size_t)(s * NV + v) * 1024;
    slab[t]       = sm[v];
    slab[512 + t] = sq[v];
  }
}

// ---------------------------------------------------------------------------
// K2: 64 blocks x 512 thr. Block owns 32 columns. Thread (g=t>>5 in 0..15,
// cl=t&31): partial su/sq for column c over slabs g::16 (coalesced,
// L2/L3-resident). LDS-reduce over g; g==0 finishes stats + per-column loss;
// 32-lane shuffle reduce; one atomicAdd per block.
// ---------------------------------------------------------------------------
__global__ __launch_bounds__(512) void k2_finish(
    const float* __restrict__ part, const float* __restrict__ cnt,
    const float* __restrict__ cmean, const float* __restrict__ cstd,
    float* __restrict__ out) {
  const int t = threadIdx.x;
  const int g = t >> 5;
  const int cl = t & 31;
  const int c = blockIdx.x * 32 + cl;

  // ---- total counts: thread t sums segment t's 6 counts, block-reduce ----
  float c6[NV];
#pragma unroll
  for (int v = 0; v < NV; ++v) c6[v] = cnt[t * 8 + v];
#pragma unroll
  for (int v = 0; v < NV; ++v)
    for (int o = 32; o > 0; o >>= 1) c6[v] += __shfl_down(c6[v], o, 64);
  __shared__ float lcnt[8][NV];
  __shared__ float cntS[NV];
  const int lane = t & 63, w = t >> 6;
  if (lane == 0)
#pragma unroll
    for (int v = 0; v < NV; ++v) lcnt[w][v] = c6[v];
  __syncthreads();
  if (t < NV) {
    float sc = 0.f;
#pragma unroll
    for (int i = 0; i < 8; ++i) sc += lcnt[i][t];
    cntS[t] = sc;
  }
  __syncthreads();

  float cnt_r[NV], nvalid = 0.f;
#pragma unroll
  for (int v = 0; v < NV; ++v) {
    cnt_r[v] = cntS[v];
    nvalid += (cnt_r[v] > 1.5f) ? 1.f : 0.f;
  }

  // ---- partial column sums over this thread's 32 slabs ----
  float su[NV] = {0.f, 0.f, 0.f, 0.f, 0.f, 0.f};
  float sq[NV] = {0.f, 0.f, 0.f, 0.f, 0.f, 0.f};
  for (int si = g; si < NBLK; si += 16) {
    const float* slab = part + (size_t)si * NV * 4096;
#pragma unroll
    for (int v = 0; v < NV; ++v) {
      su[v] += slab[v * 4096 + c];
      sq[v] += slab[v * 4096 + 2048 + c];
    }
  }

  __shared__ float red[16][32][2 * NV];   // 24 KB
#pragma unroll
  for (int v = 0; v < NV; ++v) {
    red[g][cl][v] = su[v];
    red[g][cl][NV + v] = sq[v];
  }
  __syncthreads();

  if (g == 0) {
    for (int gg = 1; gg < 16; ++gg)
#pragma unroll
      for (int v = 0; v < NV; ++v) {
        su[v] += red[gg][cl][v];
        sq[v] += red[gg][cl][NV + v];
      }

    float mean[NV], sd[NV], nm = 0.f, ns = 0.f;
#pragma unroll
    for (int v = 0; v < NV; ++v) {
      float n = fmaxf(cnt_r[v], 1.f);
      float mu = su[v] / n;
      float var = (sq[v] - cnt_r[v] * mu * mu) / fmaxf(cnt_r[v] - 1.f, 1.f);
      float sdv = sqrtf(fmaxf(var, 0.f));
      mean[v] = mu;
      sd[v] = sdv;
      if (cnt_r[v] > 1.5f) { nm += mu; ns += sdv; }
    }
    nm /= nvalid;
    ns /= nvalid;
    const float cm = cmean[c] * (1.f - MOMENT_F) + nm * MOMENT_F;
    const float cs = cstd[c]  * (1.f - MOMENT_F) + ns * MOMENT_F;

    float contrib = 0.f;
#pragma unroll
    for (int v = 0; v < NV; ++v)
      if (cnt_r[v] > 1.5f) {
        float d1 = mean[v] - cm;
        float d2 = sd[v] - cs;
        contrib += d1 * d1 + d2 * d2;
      }
    contrib /= (2.f * nvalid);

    for (int o = 16; o > 0; o >>= 1) contrib += __shfl_down(contrib, o, 32);
    if (cl == 0) atomicAdd(out, contrib);
  }
}

extern "C" void kernel_launch(void* const* d_in, const int* in_sizes, int n_in,
                              void* d_out, int out_size, void* d_ws, size_t ws_size,
                              hipStream_t stream) {
  const float* x     = (const float*)d_in[0];  // (N, C) f32
  const float* cmean = (const float*)d_in[1];  // (C,)  f32
  const float* cstd  = (const float*)d_in[2];  // (C,)  f32
  const int*   views = (const int*)d_in[3];    // (N,)  i32
  float* out = (float*)d_out;

  float* part = (float*)d_ws;
  float* cnt  = part + (size_t)NBLK * NV * 4096;

  k1_stats<<<NBLK, 512, 0, stream>>>(x, views, (float4*)part, cnt, out);
  k2_finish<<<CC / 32, 512, 0, stream>>>(part, cnt, cmean, cstd, out);
}